// Round 9
// baseline (442.630 us; speedup 1.0000x reference)
//
#include <hip/hip_runtime.h>
#include <math.h>

#define SDIM 512
#define BDIM 64
#define HDIM 512
#define TDIM 32
#define MTOT (SDIM * BDIM)

typedef __attribute__((ext_vector_type(8))) short bf16x8;
typedef __attribute__((ext_vector_type(4))) float f32x4;

// static device scratch
__device__ unsigned short g_w1hT[HDIM * HDIM];  // W1^T hi [n][k]
__device__ unsigned short g_w1lT[HDIM * HDIM];  // W1^T lo [n][k]
__device__ unsigned short g_w2hT[TDIM * HDIM];  // W2^T hi [t][k]
__device__ unsigned short g_w2lT[TDIM * HDIM];  // W2^T lo [t][k]
__device__ float g_em[(size_t)MTOT * TDIM];     // 4 MB emissions, b-major

__device__ __forceinline__ unsigned short f2bf(float x) {
  union { float f; unsigned int u; } v; v.f = x;
  unsigned int r = v.u + 0x7FFFu + ((v.u >> 16) & 1u);  // RNE
  return (unsigned short)(r >> 16);
}
__device__ __forceinline__ float bf2f(unsigned short h) {
  union { float f; unsigned int u; } v; v.u = ((unsigned int)h) << 16; return v.f;
}

// ---------------- W1/W2 split + transpose ----------------
__global__ void split_kernel(const float* __restrict__ W1, const float* __restrict__ W2) {
  const int n = blockIdx.x;
  const int k0 = threadIdx.x * 4;
  if (n < HDIM) {
    ushort4 h, l; float x;
    x = W1[(size_t)(k0 + 0) * HDIM + n]; h.x = f2bf(x); l.x = f2bf(x - bf2f(h.x));
    x = W1[(size_t)(k0 + 1) * HDIM + n]; h.y = f2bf(x); l.y = f2bf(x - bf2f(h.y));
    x = W1[(size_t)(k0 + 2) * HDIM + n]; h.z = f2bf(x); l.z = f2bf(x - bf2f(h.z));
    x = W1[(size_t)(k0 + 3) * HDIM + n]; h.w = f2bf(x); l.w = f2bf(x - bf2f(h.w));
    *(ushort4*)&g_w1hT[(size_t)n * HDIM + k0] = h;
    *(ushort4*)&g_w1lT[(size_t)n * HDIM + k0] = l;
  } else {
    const int t = n - HDIM;
    ushort4 h, l; float x;
    x = W2[(size_t)(k0 + 0) * TDIM + t]; h.x = f2bf(x); l.x = f2bf(x - bf2f(h.x));
    x = W2[(size_t)(k0 + 1) * TDIM + t]; h.y = f2bf(x); l.y = f2bf(x - bf2f(h.y));
    x = W2[(size_t)(k0 + 2) * TDIM + t]; h.z = f2bf(x); l.z = f2bf(x - bf2f(h.z));
    x = W2[(size_t)(k0 + 3) * TDIM + t]; h.w = f2bf(x); l.w = f2bf(x - bf2f(h.w));
    *(ushort4*)&g_w2hT[(size_t)t * HDIM + k0] = h;
    *(ushort4*)&g_w2lT[(size_t)t * HDIM + k0] = l;
  }
}

// ---------------- Fused emissions (unchanged, proven) ----------------
__global__ __launch_bounds__(256) void emis_kernel(
    const float* __restrict__ hidden, const float* __restrict__ b1,
    const float* __restrict__ b2)
{
  __shared__ unsigned short lAh[64][40];
  __shared__ unsigned short lAl[64][40];
  __shared__ unsigned short lBh[128][40];
  __shared__ unsigned short lBl[128][40];
  __shared__ unsigned short H1h[64][136];
  __shared__ unsigned short H1l[64][136];

  const int tid = threadIdx.x;
  const int s = blockIdx.x;
  const int row0 = s * 64;
  const int wave = tid >> 6;
  const int lane = tid & 63;
  const int l15 = lane & 15;
  const int l4 = lane >> 4;
  const int wr1 = (wave >> 1) * 32;
  const int wc1 = (wave & 1) * 64;

  f32x4 acc_em[2];
  acc_em[0] = (f32x4)(0.f);
  acc_em[1] = (f32x4)(0.f);

  for (int jcb = 0; jcb < 4; ++jcb) {
    const int jc = jcb * 128;

    f32x4 acc1[2][4];
#pragma unroll
    for (int i = 0; i < 2; ++i)
#pragma unroll
      for (int j = 0; j < 4; ++j) acc1[i][j] = (f32x4)(0.f);

    for (int k0 = 0; k0 < HDIM; k0 += 32) {
#pragma unroll
      for (int i = 0; i < 2; ++i) {
        int f4 = tid + 256 * i;
        int r = f4 >> 3, q = f4 & 7;
        float4 v = *(const float4*)&hidden[(size_t)(row0 + r) * HDIM + k0 + 4 * q];
        ushort4 h, l;
        h.x = f2bf(v.x); l.x = f2bf(v.x - bf2f(h.x));
        h.y = f2bf(v.y); l.y = f2bf(v.y - bf2f(h.y));
        h.z = f2bf(v.z); l.z = f2bf(v.z - bf2f(h.z));
        h.w = f2bf(v.w); l.w = f2bf(v.w - bf2f(h.w));
        *(ushort4*)&lAh[r][4 * q] = h;
        *(ushort4*)&lAl[r][4 * q] = l;
      }
#pragma unroll
      for (int i = 0; i < 2; ++i) {
        int f8 = tid + 256 * i;
        int nl = f8 >> 2, kq8 = f8 & 3;
        *(uint4*)&lBh[nl][8 * kq8] =
            *(const uint4*)&g_w1hT[(size_t)(jc + nl) * HDIM + k0 + 8 * kq8];
        *(uint4*)&lBl[nl][8 * kq8] =
            *(const uint4*)&g_w1lT[(size_t)(jc + nl) * HDIM + k0 + 8 * kq8];
      }
      __syncthreads();

      bf16x8 aH[2], aL[2];
#pragma unroll
      for (int i = 0; i < 2; ++i) {
        aH[i] = *(const bf16x8*)&lAh[wr1 + 16 * i + l15][8 * l4];
        aL[i] = *(const bf16x8*)&lAl[wr1 + 16 * i + l15][8 * l4];
      }
#pragma unroll
      for (int j = 0; j < 4; ++j) {
        bf16x8 bH = *(const bf16x8*)&lBh[wc1 + 16 * j + l15][8 * l4];
        bf16x8 bL = *(const bf16x8*)&lBl[wc1 + 16 * j + l15][8 * l4];
#pragma unroll
        for (int i = 0; i < 2; ++i) {
          acc1[i][j] = __builtin_amdgcn_mfma_f32_16x16x32_bf16(aH[i], bH, acc1[i][j], 0, 0, 0);
          acc1[i][j] = __builtin_amdgcn_mfma_f32_16x16x32_bf16(aH[i], bL, acc1[i][j], 0, 0, 0);
          acc1[i][j] = __builtin_amdgcn_mfma_f32_16x16x32_bf16(aL[i], bH, acc1[i][j], 0, 0, 0);
        }
      }
      __syncthreads();
    }

#pragma unroll
    for (int j = 0; j < 4; ++j) {
      const int col = wc1 + 16 * j + l15;
      const float bv = b1[jc + col];
#pragma unroll
      for (int i = 0; i < 2; ++i) {
#pragma unroll
        for (int r = 0; r < 4; ++r) {
          int lrow = wr1 + 16 * i + 4 * l4 + r;
          float h = 1.f / (1.f + expf(-(acc1[i][j][r] + bv)));
          unsigned short hh = f2bf(h);
          unsigned short hl = f2bf(h - bf2f(hh));
          H1h[lrow][col] = hh;
          H1l[lrow][col] = hl;
        }
      }
    }
    __syncthreads();

#pragma unroll
    for (int ks = 0; ks < 4; ++ks) {
      bf16x8 aH2 = *(const bf16x8*)&H1h[16 * wave + l15][32 * ks + 8 * l4];
      bf16x8 aL2 = *(const bf16x8*)&H1l[16 * wave + l15][32 * ks + 8 * l4];
#pragma unroll
      for (int j2 = 0; j2 < 2; ++j2) {
        const size_t wo = (size_t)(16 * j2 + l15) * HDIM + jc + 32 * ks + 8 * l4;
        bf16x8 bH2 = *(const bf16x8*)&g_w2hT[wo];
        bf16x8 bL2 = *(const bf16x8*)&g_w2lT[wo];
        acc_em[j2] = __builtin_amdgcn_mfma_f32_16x16x32_bf16(aH2, bH2, acc_em[j2], 0, 0, 0);
        acc_em[j2] = __builtin_amdgcn_mfma_f32_16x16x32_bf16(aH2, bL2, acc_em[j2], 0, 0, 0);
        acc_em[j2] = __builtin_amdgcn_mfma_f32_16x16x32_bf16(aL2, bH2, acc_em[j2], 0, 0, 0);
      }
    }
    __syncthreads();
  }

#pragma unroll
  for (int j2 = 0; j2 < 2; ++j2) {
    const int t = 16 * j2 + l15;
    const float bv = b2[t];
#pragma unroll
    for (int r = 0; r < 4; ++r) {
      int b = 16 * wave + 4 * l4 + r;
      g_em[((size_t)b * SDIM + s) * TDIM + t] = acc_em[j2][r] + bv;
    }
  }
}

// ---------------- Viterbi v3: 2 chains/wave, 64-lane split argmax, LDS-chunked em ----------------
__global__ __launch_bounds__(64) void viterbi_kernel(
    const int* __restrict__ lens, const float* __restrict__ trans,
    float* __restrict__ out)
{
  __shared__ float emL[2][2][32][32];           // [chain][buf][step][tag] 16 KB
  __shared__ unsigned char bps[2][SDIM][TDIM];  // 32 KB
  __shared__ float fvL[2][32];

  const int lane = threadIdx.x;
  const int c = lane & 31;       // curr tag owned by this lane
  const int ph = lane >> 5;      // prev-half: p in [16ph, 16ph+16)
  const int p0 = 16 * ph;
  const int bA = 2 * blockIdx.x;
  const int bB = bA + 1;

  // tr[p] = trans[c][p0+p] — chain-independent
  float tr[16];
#pragma unroll
  for (int p = 0; p < 16; p += 4) {
    float4 t4 = *(const float4*)&trans[c * TDIM + p0 + p];
    tr[p] = t4.x; tr[p + 1] = t4.y; tr[p + 2] = t4.z; tr[p + 3] = t4.w;
  }

  int lenA, lenB;
  {
    const int* p32 = lens;
    if (p32[1] == 0) {
      lenA = (int)((const long long*)lens)[bA];
      lenB = (int)((const long long*)lens)[bB];
    } else { lenA = p32[bA]; lenB = p32[bB]; }
  }

  const float* emA = g_em + (size_t)bA * SDIM * TDIM;
  const float* emB = g_em + (size_t)bB * SDIM * TDIM;

  float4 stA[4], stB[4];
  // prologue: load chunk 0
#pragma unroll
  for (int i = 0; i < 4; ++i) {
    stA[i] = *(const float4*)&emA[4 * (lane + 64 * i)];
    stB[i] = *(const float4*)&emB[4 * (lane + 64 * i)];
  }
  // write chunk 0 -> buf 0
#pragma unroll
  for (int i = 0; i < 4; ++i) {
    ((float4*)&emL[0][0][0][0])[lane + 64 * i] = stA[i];
    ((float4*)&emL[1][0][0][0])[lane + 64 * i] = stB[i];
  }
  // issue chunk 1
#pragma unroll
  for (int i = 0; i < 4; ++i) {
    stA[i] = *(const float4*)&emA[1024 + 4 * (lane + 64 * i)];
    stB[i] = *(const float4*)&emB[1024 + 4 * (lane + 64 * i)];
  }

  float fvA = emL[0][0][0][c];
  float fvB = emL[1][0][0][c];
  fvL[ph][c] = ph ? fvB : fvA;  // A by ph0 lanes, B by ph1 lanes

// one chain's step: read fv vector half, add tr, 16-way argmax, cross-half merge
#define VPHASE(CH, fvv, lenv)                                                   \
  {                                                                             \
    const float* fvb = &fvL[CH][p0];                                            \
    float4 r0 = *(const float4*)(fvb + 0);                                      \
    float4 r1 = *(const float4*)(fvb + 4);                                      \
    float4 r2 = *(const float4*)(fvb + 8);                                      \
    float4 r3 = *(const float4*)(fvb + 12);                                     \
    float e = emL[CH][bufc][tm][c];                                             \
    float s0 = r0.x + tr[0], s1 = r0.y + tr[1], s2 = r0.z + tr[2], s3 = r0.w + tr[3];   \
    float s4 = r1.x + tr[4], s5 = r1.y + tr[5], s6 = r1.z + tr[6], s7 = r1.w + tr[7];   \
    float s8 = r2.x + tr[8], s9 = r2.y + tr[9], s10 = r2.z + tr[10], s11 = r2.w + tr[11]; \
    float s12 = r3.x + tr[12], s13 = r3.y + tr[13], s14 = r3.z + tr[14], s15 = r3.w + tr[15]; \
    float ca = s0; int ia = p0 + 0;                                             \
    if (s1 > ca) { ca = s1; ia = p0 + 1; }                                      \
    if (s2 > ca) { ca = s2; ia = p0 + 2; }                                      \
    if (s3 > ca) { ca = s3; ia = p0 + 3; }                                      \
    float cb = s4; int ib = p0 + 4;                                             \
    if (s5 > cb) { cb = s5; ib = p0 + 5; }                                      \
    if (s6 > cb) { cb = s6; ib = p0 + 6; }                                      \
    if (s7 > cb) { cb = s7; ib = p0 + 7; }                                      \
    float cc = s8; int ic = p0 + 8;                                             \
    if (s9 > cc) { cc = s9; ic = p0 + 9; }                                      \
    if (s10 > cc) { cc = s10; ic = p0 + 10; }                                   \
    if (s11 > cc) { cc = s11; ic = p0 + 11; }                                   \
    float cd = s12; int id_ = p0 + 12;                                          \
    if (s13 > cd) { cd = s13; id_ = p0 + 13; }                                  \
    if (s14 > cd) { cd = s14; id_ = p0 + 14; }                                  \
    if (s15 > cd) { cd = s15; id_ = p0 + 15; }                                  \
    if (cb > ca) { ca = cb; ia = ib; }                                          \
    if (cd > cc) { cc = cd; ic = id_; }                                         \
    if (cc > ca) { ca = cc; ia = ic; }                                          \
    float om = __shfl_xor(ca, 32, 64);                                          \
    int oi = __shfl_xor(ia, 32, 64);                                            \
    if (om > ca || (om == ca && oi < ia)) { ca = om; ia = oi; }                 \
    const bool act = (t < lenv);                                                \
    fvv = act ? (ca + e) : fvv;                                                 \
    int bp = act ? ia : c;                                                      \
    if (ph == CH) { fvL[CH][c] = fvv; bps[CH][t][c] = (unsigned char)bp; }      \
  }

  for (int t = 1; t < SDIM; ++t) {
    if ((t & 31) == 0) {
      const int buf = (t >> 5) & 1;
#pragma unroll
      for (int i = 0; i < 4; ++i) {
        ((float4*)&emL[0][buf][0][0])[lane + 64 * i] = stA[i];
        ((float4*)&emL[1][buf][0][0])[lane + 64 * i] = stB[i];
      }
      const int nc = (t >> 5) + 1;
      if (nc < 16) {
#pragma unroll
        for (int i = 0; i < 4; ++i) {
          stA[i] = *(const float4*)&emA[nc * 1024 + 4 * (lane + 64 * i)];
          stB[i] = *(const float4*)&emB[nc * 1024 + 4 * (lane + 64 * i)];
        }
      }
    }
    const int tm = t & 31;
    const int bufc = (t >> 5) & 1;
    VPHASE(0, fvA, lenA)
    VPHASE(1, fvB, lenB)
  }
#undef VPHASE

  // final argmax per chain (values duplicated across halves; width-32 reduce)
  float bsA = fvA; int biA = c;
  float bsB = fvB; int biB = c;
#pragma unroll
  for (int off = 16; off > 0; off >>= 1) {
    float oa = __shfl_down(bsA, off, 32); int ja = __shfl_down(biA, off, 32);
    if (oa > bsA || (oa == bsA && ja < biA)) { bsA = oa; biA = ja; }
    float ob = __shfl_down(bsB, off, 32); int jb = __shfl_down(biB, off, 32);
    if (ob > bsB || (ob == bsB && jb < biB)) { bsB = ob; biB = jb; }
  }
  bsA = __shfl(bsA, 0, 32); int tagA = __shfl(biA, 0, 32);
  bsB = __shfl(bsB, 0, 32); int tagB = __shfl(biB, 0, 32);

  if (lane == 0) {
    out[(size_t)SDIM * BDIM + bA] = bsA;
    out[(size_t)SDIM * BDIM + bB] = bsB;
    out[(size_t)(SDIM - 1) * BDIM + bA] = (float)tagA;
    out[(size_t)(SDIM - 1) * BDIM + bB] = (float)tagB;
  }

  // backtrack both chains: prefetch 4 rows, 1 shfl per chain per step
  for (int t = SDIM - 1; t >= 1; t -= 4) {
    int a0 = bps[0][t][c], b0 = bps[1][t][c];
    int a1 = (t - 1 >= 1) ? bps[0][t - 1][c] : 0, b1 = (t - 1 >= 1) ? bps[1][t - 1][c] : 0;
    int a2 = (t - 2 >= 1) ? bps[0][t - 2][c] : 0, b2 = (t - 2 >= 1) ? bps[1][t - 2][c] : 0;
    int a3 = (t - 3 >= 1) ? bps[0][t - 3][c] : 0, b3 = (t - 3 >= 1) ? bps[1][t - 3][c] : 0;
    tagA = __shfl(a0, tagA, 32); tagB = __shfl(b0, tagB, 32);
    if (lane == 0) {
      out[(size_t)(t - 1) * BDIM + bA] = (float)tagA;
      out[(size_t)(t - 1) * BDIM + bB] = (float)tagB;
    }
    if (t - 1 >= 1) {
      tagA = __shfl(a1, tagA, 32); tagB = __shfl(b1, tagB, 32);
      if (lane == 0) {
        out[(size_t)(t - 2) * BDIM + bA] = (float)tagA;
        out[(size_t)(t - 2) * BDIM + bB] = (float)tagB;
      }
    }
    if (t - 2 >= 1) {
      tagA = __shfl(a2, tagA, 32); tagB = __shfl(b2, tagB, 32);
      if (lane == 0) {
        out[(size_t)(t - 3) * BDIM + bA] = (float)tagA;
        out[(size_t)(t - 3) * BDIM + bB] = (float)tagB;
      }
    }
    if (t - 3 >= 1) {
      tagA = __shfl(a3, tagA, 32); tagB = __shfl(b3, tagB, 32);
      if (lane == 0) {
        out[(size_t)(t - 4) * BDIM + bA] = (float)tagA;
        out[(size_t)(t - 4) * BDIM + bB] = (float)tagB;
      }
    }
  }
}

// ---------------- host ----------------
static int find_by_size(const int* in_sizes, int n_in, int sz, int fb) {
  for (int i = 0; i < n_in; ++i) if (in_sizes[i] == sz) return i;
  return fb;
}

extern "C" void kernel_launch(void* const* d_in, const int* in_sizes, int n_in,
                              void* d_out, int out_size, void* d_ws, size_t ws_size,
                              hipStream_t stream) {
  const int i_hidden = find_by_size(in_sizes, n_in, SDIM * BDIM * HDIM, 0);
  const int i_lens   = find_by_size(in_sizes, n_in, BDIM, 1);
  const int i_W1     = find_by_size(in_sizes, n_in, HDIM * HDIM, 3);
  const int i_b1     = find_by_size(in_sizes, n_in, HDIM, 4);
  const int i_W2     = find_by_size(in_sizes, n_in, HDIM * TDIM, 5);
  const int i_b2     = find_by_size(in_sizes, n_in, TDIM, 6);
  const int i_tr     = find_by_size(in_sizes, n_in, TDIM * TDIM, 7);

  const float* hidden = (const float*)d_in[i_hidden];
  const int*   lens   = (const int*)d_in[i_lens];
  const float* W1     = (const float*)d_in[i_W1];
  const float* b1     = (const float*)d_in[i_b1];
  const float* W2     = (const float*)d_in[i_W2];
  const float* b2     = (const float*)d_in[i_b2];
  const float* trans  = (const float*)d_in[i_tr];
  float* out = (float*)d_out;

  split_kernel<<<HDIM + TDIM, 128, 0, stream>>>(W1, W2);
  emis_kernel<<<SDIM, 256, 0, stream>>>(hidden, b1, b2);
  viterbi_kernel<<<BDIM / 2, 64, 0, stream>>>(lens, trans, out);
}

// Round 10
// 313.036 us; speedup vs baseline: 1.4140x; 1.4140x over previous
//
#include <hip/hip_runtime.h>
#include <math.h>

#define SDIM 512
#define BDIM 64
#define HDIM 512
#define TDIM 32
#define MTOT (SDIM * BDIM)

typedef __attribute__((ext_vector_type(8))) short bf16x8;
typedef __attribute__((ext_vector_type(4))) float f32x4;

// static device scratch
__device__ unsigned short g_w1hT[HDIM * HDIM];  // W1^T hi [n][k]
__device__ unsigned short g_w1lT[HDIM * HDIM];  // W1^T lo [n][k]
__device__ unsigned short g_w2hT[TDIM * HDIM];  // W2^T hi [t][k]
__device__ unsigned short g_w2lT[TDIM * HDIM];  // W2^T lo [t][k]
__device__ float g_em[(size_t)MTOT * TDIM];     // 4 MB emissions, b-major

__device__ __forceinline__ unsigned short f2bf(float x) {
  union { float f; unsigned int u; } v; v.f = x;
  unsigned int r = v.u + 0x7FFFu + ((v.u >> 16) & 1u);  // RNE
  return (unsigned short)(r >> 16);
}
__device__ __forceinline__ float bf2f(unsigned short h) {
  union { float f; unsigned int u; } v; v.u = ((unsigned int)h) << 16; return v.f;
}
__device__ __forceinline__ float readlane_f(float v, int l) {
  return __int_as_float(__builtin_amdgcn_readlane(__float_as_int(v), l));
}

// ---------------- W1/W2 split + transpose ----------------
__global__ void split_kernel(const float* __restrict__ W1, const float* __restrict__ W2) {
  const int n = blockIdx.x;
  const int k0 = threadIdx.x * 4;
  if (n < HDIM) {
    ushort4 h, l; float x;
    x = W1[(size_t)(k0 + 0) * HDIM + n]; h.x = f2bf(x); l.x = f2bf(x - bf2f(h.x));
    x = W1[(size_t)(k0 + 1) * HDIM + n]; h.y = f2bf(x); l.y = f2bf(x - bf2f(h.y));
    x = W1[(size_t)(k0 + 2) * HDIM + n]; h.z = f2bf(x); l.z = f2bf(x - bf2f(h.z));
    x = W1[(size_t)(k0 + 3) * HDIM + n]; h.w = f2bf(x); l.w = f2bf(x - bf2f(h.w));
    *(ushort4*)&g_w1hT[(size_t)n * HDIM + k0] = h;
    *(ushort4*)&g_w1lT[(size_t)n * HDIM + k0] = l;
  } else {
    const int t = n - HDIM;
    ushort4 h, l; float x;
    x = W2[(size_t)(k0 + 0) * TDIM + t]; h.x = f2bf(x); l.x = f2bf(x - bf2f(h.x));
    x = W2[(size_t)(k0 + 1) * TDIM + t]; h.y = f2bf(x); l.y = f2bf(x - bf2f(h.y));
    x = W2[(size_t)(k0 + 2) * TDIM + t]; h.z = f2bf(x); l.z = f2bf(x - bf2f(h.z));
    x = W2[(size_t)(k0 + 3) * TDIM + t]; h.w = f2bf(x); l.w = f2bf(x - bf2f(h.w));
    *(ushort4*)&g_w2hT[(size_t)t * HDIM + k0] = h;
    *(ushort4*)&g_w2lT[(size_t)t * HDIM + k0] = l;
  }
}

// ---------------- Fused emissions (unchanged, proven) ----------------
__global__ __launch_bounds__(256) void emis_kernel(
    const float* __restrict__ hidden, const float* __restrict__ b1,
    const float* __restrict__ b2)
{
  __shared__ unsigned short lAh[64][40];
  __shared__ unsigned short lAl[64][40];
  __shared__ unsigned short lBh[128][40];
  __shared__ unsigned short lBl[128][40];
  __shared__ unsigned short H1h[64][136];
  __shared__ unsigned short H1l[64][136];

  const int tid = threadIdx.x;
  const int s = blockIdx.x;
  const int row0 = s * 64;
  const int wave = tid >> 6;
  const int lane = tid & 63;
  const int l15 = lane & 15;
  const int l4 = lane >> 4;
  const int wr1 = (wave >> 1) * 32;
  const int wc1 = (wave & 1) * 64;

  f32x4 acc_em[2];
  acc_em[0] = (f32x4)(0.f);
  acc_em[1] = (f32x4)(0.f);

  for (int jcb = 0; jcb < 4; ++jcb) {
    const int jc = jcb * 128;

    f32x4 acc1[2][4];
#pragma unroll
    for (int i = 0; i < 2; ++i)
#pragma unroll
      for (int j = 0; j < 4; ++j) acc1[i][j] = (f32x4)(0.f);

    for (int k0 = 0; k0 < HDIM; k0 += 32) {
#pragma unroll
      for (int i = 0; i < 2; ++i) {
        int f4 = tid + 256 * i;
        int r = f4 >> 3, q = f4 & 7;
        float4 v = *(const float4*)&hidden[(size_t)(row0 + r) * HDIM + k0 + 4 * q];
        ushort4 h, l;
        h.x = f2bf(v.x); l.x = f2bf(v.x - bf2f(h.x));
        h.y = f2bf(v.y); l.y = f2bf(v.y - bf2f(h.y));
        h.z = f2bf(v.z); l.z = f2bf(v.z - bf2f(h.z));
        h.w = f2bf(v.w); l.w = f2bf(v.w - bf2f(h.w));
        *(ushort4*)&lAh[r][4 * q] = h;
        *(ushort4*)&lAl[r][4 * q] = l;
      }
#pragma unroll
      for (int i = 0; i < 2; ++i) {
        int f8 = tid + 256 * i;
        int nl = f8 >> 2, kq8 = f8 & 3;
        *(uint4*)&lBh[nl][8 * kq8] =
            *(const uint4*)&g_w1hT[(size_t)(jc + nl) * HDIM + k0 + 8 * kq8];
        *(uint4*)&lBl[nl][8 * kq8] =
            *(const uint4*)&g_w1lT[(size_t)(jc + nl) * HDIM + k0 + 8 * kq8];
      }
      __syncthreads();

      bf16x8 aH[2], aL[2];
#pragma unroll
      for (int i = 0; i < 2; ++i) {
        aH[i] = *(const bf16x8*)&lAh[wr1 + 16 * i + l15][8 * l4];
        aL[i] = *(const bf16x8*)&lAl[wr1 + 16 * i + l15][8 * l4];
      }
#pragma unroll
      for (int j = 0; j < 4; ++j) {
        bf16x8 bH = *(const bf16x8*)&lBh[wc1 + 16 * j + l15][8 * l4];
        bf16x8 bL = *(const bf16x8*)&lBl[wc1 + 16 * j + l15][8 * l4];
#pragma unroll
        for (int i = 0; i < 2; ++i) {
          acc1[i][j] = __builtin_amdgcn_mfma_f32_16x16x32_bf16(aH[i], bH, acc1[i][j], 0, 0, 0);
          acc1[i][j] = __builtin_amdgcn_mfma_f32_16x16x32_bf16(aH[i], bL, acc1[i][j], 0, 0, 0);
          acc1[i][j] = __builtin_amdgcn_mfma_f32_16x16x32_bf16(aL[i], bH, acc1[i][j], 0, 0, 0);
        }
      }
      __syncthreads();
    }

#pragma unroll
    for (int j = 0; j < 4; ++j) {
      const int col = wc1 + 16 * j + l15;
      const float bv = b1[jc + col];
#pragma unroll
      for (int i = 0; i < 2; ++i) {
#pragma unroll
        for (int r = 0; r < 4; ++r) {
          int lrow = wr1 + 16 * i + 4 * l4 + r;
          float h = 1.f / (1.f + expf(-(acc1[i][j][r] + bv)));
          unsigned short hh = f2bf(h);
          unsigned short hl = f2bf(h - bf2f(hh));
          H1h[lrow][col] = hh;
          H1l[lrow][col] = hl;
        }
      }
    }
    __syncthreads();

#pragma unroll
    for (int ks = 0; ks < 4; ++ks) {
      bf16x8 aH2 = *(const bf16x8*)&H1h[16 * wave + l15][32 * ks + 8 * l4];
      bf16x8 aL2 = *(const bf16x8*)&H1l[16 * wave + l15][32 * ks + 8 * l4];
#pragma unroll
      for (int j2 = 0; j2 < 2; ++j2) {
        const size_t wo = (size_t)(16 * j2 + l15) * HDIM + jc + 32 * ks + 8 * l4;
        bf16x8 bH2 = *(const bf16x8*)&g_w2hT[wo];
        bf16x8 bL2 = *(const bf16x8*)&g_w2lT[wo];
        acc_em[j2] = __builtin_amdgcn_mfma_f32_16x16x32_bf16(aH2, bH2, acc_em[j2], 0, 0, 0);
        acc_em[j2] = __builtin_amdgcn_mfma_f32_16x16x32_bf16(aH2, bL2, acc_em[j2], 0, 0, 0);
        acc_em[j2] = __builtin_amdgcn_mfma_f32_16x16x32_bf16(aL2, bH2, acc_em[j2], 0, 0, 0);
      }
    }
    __syncthreads();
  }

#pragma unroll
  for (int j2 = 0; j2 < 2; ++j2) {
    const int t = 16 * j2 + l15;
    const float bv = b2[t];
#pragma unroll
    for (int r = 0; r < 4; ++r) {
      int b = 16 * wave + 4 * l4 + r;
      g_em[((size_t)b * SDIM + s) * TDIM + t] = acc_em[j2][r] + bv;
    }
  }
}

// ---------------- Viterbi v4: fv in SGPRs via readlane, 1 chain / block ----------------
__global__ __launch_bounds__(64) void viterbi_kernel(
    const int* __restrict__ lens, const float* __restrict__ trans,
    float* __restrict__ out)
{
  __shared__ unsigned char bps[SDIM][TDIM];  // 16 KB
  const int b = blockIdx.x;
  const int lane = threadIdx.x;
  const int c = lane & 31;

  // tr[p] = trans[c][p] (this lane's destination-tag row)
  float tr[TDIM];
#pragma unroll
  for (int p = 0; p < TDIM; p += 4) {
    float4 t4 = *(const float4*)&trans[c * TDIM + p];
    tr[p] = t4.x; tr[p + 1] = t4.y; tr[p + 2] = t4.z; tr[p + 3] = t4.w;
  }

  int len;
  { const int* p32 = lens;
    len = (p32[1] == 0) ? (int)((const long long*)lens)[b] : p32[b]; }

  const float* em = g_em + (size_t)b * SDIM * TDIM;

  float fvown = em[c];  // fv[c] at t=0
  // uniform (SGPR) replica of the full fv vector
  float sfv[TDIM];
#pragma unroll
  for (int p = 0; p < TDIM; ++p) sfv[p] = readlane_f(fvown, p);

  float e_cur = em[TDIM + c];      // t = 1
  float e_nxt = em[2 * TDIM + c];  // t = 2

  int t = 1;
  for (; t < SDIM; ++t) {
    if (t >= len) break;  // frozen for the rest (uniform branch)

    // candidates: uniform fv + per-lane tr
    float sv[TDIM];
#pragma unroll
    for (int p = 0; p < TDIM; ++p) sv[p] = sfv[p] + tr[p];

    // blocked argmax, first-index-wins (proven pattern)
    float c0 = sv[0], c1 = sv[8], c2 = sv[16], c3 = sv[24];
    int i0 = 0, i1 = 8, i2 = 16, i3 = 24;
#pragma unroll
    for (int q = 1; q < 8; ++q) {
      if (sv[q]      > c0) { c0 = sv[q];      i0 = q; }
      if (sv[8 + q]  > c1) { c1 = sv[8 + q];  i1 = 8 + q; }
      if (sv[16 + q] > c2) { c2 = sv[16 + q]; i2 = 16 + q; }
      if (sv[24 + q] > c3) { c3 = sv[24 + q]; i3 = 24 + q; }
    }
    if (c1 > c0) { c0 = c1; i0 = i1; }
    if (c2 > c0) { c0 = c2; i0 = i2; }
    if (c3 > c0) { c0 = c3; i0 = i3; }

    fvown = c0 + e_cur;
    if (lane < TDIM) bps[t][c] = (unsigned char)i0;

    // refresh the uniform fv replica (32 independent readlanes, ~40 cy)
#pragma unroll
    for (int p = 0; p < TDIM; ++p) sfv[p] = readlane_f(fvown, p);

    e_cur = e_nxt;
    int tn = (t + 2 < SDIM) ? t + 2 : SDIM - 1;
    e_nxt = em[(size_t)tn * TDIM + c];
  }

  // identity backpointers for the frozen tail
  for (int lt = t; lt < SDIM; ++lt)
    if (lane < TDIM) bps[lt][c] = (unsigned char)c;

  // final argmax over tags (lowest index wins)
  float bs = fvown;
  int bi = c;
#pragma unroll
  for (int off = 16; off > 0; off >>= 1) {
    float os = __shfl_down(bs, off, 32);
    int oi = __shfl_down(bi, off, 32);
    if (os > bs || (os == bs && oi < bi)) { bs = os; bi = oi; }
  }
  bs = __shfl(bs, 0, 32);
  int tag = __shfl(bi, 0, 32);

  __syncthreads();

  if (lane == 0) {
    out[(size_t)SDIM * BDIM + b] = bs;
    out[(size_t)(SDIM - 1) * BDIM + b] = (float)tag;
  }

  // backtrack: 4-row prefetch + shfl select (proven round-8 pattern)
  for (int tt = SDIM - 1; tt >= 1; tt -= 4) {
    int r0v = bps[tt][c];
    int r1v = (tt - 1 >= 1) ? bps[tt - 1][c] : 0;
    int r2v = (tt - 2 >= 1) ? bps[tt - 2][c] : 0;
    int r3v = (tt - 3 >= 1) ? bps[tt - 3][c] : 0;
    tag = __shfl(r0v, tag, 32);
    if (lane == 0) out[(size_t)(tt - 1) * BDIM + b] = (float)tag;
    if (tt - 1 >= 1) {
      tag = __shfl(r1v, tag, 32);
      if (lane == 0) out[(size_t)(tt - 2) * BDIM + b] = (float)tag;
    }
    if (tt - 2 >= 1) {
      tag = __shfl(r2v, tag, 32);
      if (lane == 0) out[(size_t)(tt - 3) * BDIM + b] = (float)tag;
    }
    if (tt - 3 >= 1) {
      tag = __shfl(r3v, tag, 32);
      if (lane == 0) out[(size_t)(tt - 4) * BDIM + b] = (float)tag;
    }
  }
}

// ---------------- host ----------------
static int find_by_size(const int* in_sizes, int n_in, int sz, int fb) {
  for (int i = 0; i < n_in; ++i) if (in_sizes[i] == sz) return i;
  return fb;
}

extern "C" void kernel_launch(void* const* d_in, const int* in_sizes, int n_in,
                              void* d_out, int out_size, void* d_ws, size_t ws_size,
                              hipStream_t stream) {
  const int i_hidden = find_by_size(in_sizes, n_in, SDIM * BDIM * HDIM, 0);
  const int i_lens   = find_by_size(in_sizes, n_in, BDIM, 1);
  const int i_W1     = find_by_size(in_sizes, n_in, HDIM * HDIM, 3);
  const int i_b1     = find_by_size(in_sizes, n_in, HDIM, 4);
  const int i_W2     = find_by_size(in_sizes, n_in, HDIM * TDIM, 5);
  const int i_b2     = find_by_size(in_sizes, n_in, TDIM, 6);
  const int i_tr     = find_by_size(in_sizes, n_in, TDIM * TDIM, 7);

  const float* hidden = (const float*)d_in[i_hidden];
  const int*   lens   = (const int*)d_in[i_lens];
  const float* W1     = (const float*)d_in[i_W1];
  const float* b1     = (const float*)d_in[i_b1];
  const float* W2     = (const float*)d_in[i_W2];
  const float* b2     = (const float*)d_in[i_b2];
  const float* trans  = (const float*)d_in[i_tr];
  float* out = (float*)d_out;

  split_kernel<<<HDIM + TDIM, 128, 0, stream>>>(W1, W2);
  emis_kernel<<<SDIM, 256, 0, stream>>>(hidden, b1, b2);
  viterbi_kernel<<<BDIM, 64, 0, stream>>>(lens, trans, out);
}

// Round 11
// 300.009 us; speedup vs baseline: 1.4754x; 1.0434x over previous
//
#include <hip/hip_runtime.h>
#include <math.h>

#define SDIM 512
#define BDIM 64
#define HDIM 512
#define TDIM 32
#define MTOT (SDIM * BDIM)

typedef __attribute__((ext_vector_type(8))) short bf16x8;
typedef __attribute__((ext_vector_type(4))) float f32x4;

// static device scratch
__device__ unsigned short g_w1hT[HDIM * HDIM];  // W1^T hi [n][k]
__device__ unsigned short g_w1lT[HDIM * HDIM];  // W1^T lo [n][k]
__device__ unsigned short g_w2hT[TDIM * HDIM];  // W2^T hi [t][k]
__device__ unsigned short g_w2lT[TDIM * HDIM];  // W2^T lo [t][k]
__device__ float g_em[(size_t)MTOT * TDIM];     // 4 MB emissions, b-major

__device__ __forceinline__ unsigned short f2bf(float x) {
  union { float f; unsigned int u; } v; v.f = x;
  unsigned int r = v.u + 0x7FFFu + ((v.u >> 16) & 1u);  // RNE
  return (unsigned short)(r >> 16);
}
__device__ __forceinline__ float bf2f(unsigned short h) {
  union { float f; unsigned int u; } v; v.u = ((unsigned int)h) << 16; return v.f;
}
__device__ __forceinline__ float readlane_f(float v, int l) {
  return __int_as_float(__builtin_amdgcn_readlane(__float_as_int(v), l));
}

// ---------------- W1/W2 split + transpose ----------------
__global__ void split_kernel(const float* __restrict__ W1, const float* __restrict__ W2) {
  const int n = blockIdx.x;
  const int k0 = threadIdx.x * 4;
  if (n < HDIM) {
    ushort4 h, l; float x;
    x = W1[(size_t)(k0 + 0) * HDIM + n]; h.x = f2bf(x); l.x = f2bf(x - bf2f(h.x));
    x = W1[(size_t)(k0 + 1) * HDIM + n]; h.y = f2bf(x); l.y = f2bf(x - bf2f(h.y));
    x = W1[(size_t)(k0 + 2) * HDIM + n]; h.z = f2bf(x); l.z = f2bf(x - bf2f(h.z));
    x = W1[(size_t)(k0 + 3) * HDIM + n]; h.w = f2bf(x); l.w = f2bf(x - bf2f(h.w));
    *(ushort4*)&g_w1hT[(size_t)n * HDIM + k0] = h;
    *(ushort4*)&g_w1lT[(size_t)n * HDIM + k0] = l;
  } else {
    const int t = n - HDIM;
    ushort4 h, l; float x;
    x = W2[(size_t)(k0 + 0) * TDIM + t]; h.x = f2bf(x); l.x = f2bf(x - bf2f(h.x));
    x = W2[(size_t)(k0 + 1) * TDIM + t]; h.y = f2bf(x); l.y = f2bf(x - bf2f(h.y));
    x = W2[(size_t)(k0 + 2) * TDIM + t]; h.z = f2bf(x); l.z = f2bf(x - bf2f(h.z));
    x = W2[(size_t)(k0 + 3) * TDIM + t]; h.w = f2bf(x); l.w = f2bf(x - bf2f(h.w));
    *(ushort4*)&g_w2hT[(size_t)t * HDIM + k0] = h;
    *(ushort4*)&g_w2lT[(size_t)t * HDIM + k0] = l;
  }
}

// ---------------- Fused emissions (unchanged, proven) ----------------
__global__ __launch_bounds__(256) void emis_kernel(
    const float* __restrict__ hidden, const float* __restrict__ b1,
    const float* __restrict__ b2)
{
  __shared__ unsigned short lAh[64][40];
  __shared__ unsigned short lAl[64][40];
  __shared__ unsigned short lBh[128][40];
  __shared__ unsigned short lBl[128][40];
  __shared__ unsigned short H1h[64][136];
  __shared__ unsigned short H1l[64][136];

  const int tid = threadIdx.x;
  const int s = blockIdx.x;
  const int row0 = s * 64;
  const int wave = tid >> 6;
  const int lane = tid & 63;
  const int l15 = lane & 15;
  const int l4 = lane >> 4;
  const int wr1 = (wave >> 1) * 32;
  const int wc1 = (wave & 1) * 64;

  f32x4 acc_em[2];
  acc_em[0] = (f32x4)(0.f);
  acc_em[1] = (f32x4)(0.f);

  for (int jcb = 0; jcb < 4; ++jcb) {
    const int jc = jcb * 128;

    f32x4 acc1[2][4];
#pragma unroll
    for (int i = 0; i < 2; ++i)
#pragma unroll
      for (int j = 0; j < 4; ++j) acc1[i][j] = (f32x4)(0.f);

    for (int k0 = 0; k0 < HDIM; k0 += 32) {
#pragma unroll
      for (int i = 0; i < 2; ++i) {
        int f4 = tid + 256 * i;
        int r = f4 >> 3, q = f4 & 7;
        float4 v = *(const float4*)&hidden[(size_t)(row0 + r) * HDIM + k0 + 4 * q];
        ushort4 h, l;
        h.x = f2bf(v.x); l.x = f2bf(v.x - bf2f(h.x));
        h.y = f2bf(v.y); l.y = f2bf(v.y - bf2f(h.y));
        h.z = f2bf(v.z); l.z = f2bf(v.z - bf2f(h.z));
        h.w = f2bf(v.w); l.w = f2bf(v.w - bf2f(h.w));
        *(ushort4*)&lAh[r][4 * q] = h;
        *(ushort4*)&lAl[r][4 * q] = l;
      }
#pragma unroll
      for (int i = 0; i < 2; ++i) {
        int f8 = tid + 256 * i;
        int nl = f8 >> 2, kq8 = f8 & 3;
        *(uint4*)&lBh[nl][8 * kq8] =
            *(const uint4*)&g_w1hT[(size_t)(jc + nl) * HDIM + k0 + 8 * kq8];
        *(uint4*)&lBl[nl][8 * kq8] =
            *(const uint4*)&g_w1lT[(size_t)(jc + nl) * HDIM + k0 + 8 * kq8];
      }
      __syncthreads();

      bf16x8 aH[2], aL[2];
#pragma unroll
      for (int i = 0; i < 2; ++i) {
        aH[i] = *(const bf16x8*)&lAh[wr1 + 16 * i + l15][8 * l4];
        aL[i] = *(const bf16x8*)&lAl[wr1 + 16 * i + l15][8 * l4];
      }
#pragma unroll
      for (int j = 0; j < 4; ++j) {
        bf16x8 bH = *(const bf16x8*)&lBh[wc1 + 16 * j + l15][8 * l4];
        bf16x8 bL = *(const bf16x8*)&lBl[wc1 + 16 * j + l15][8 * l4];
#pragma unroll
        for (int i = 0; i < 2; ++i) {
          acc1[i][j] = __builtin_amdgcn_mfma_f32_16x16x32_bf16(aH[i], bH, acc1[i][j], 0, 0, 0);
          acc1[i][j] = __builtin_amdgcn_mfma_f32_16x16x32_bf16(aH[i], bL, acc1[i][j], 0, 0, 0);
          acc1[i][j] = __builtin_amdgcn_mfma_f32_16x16x32_bf16(aL[i], bH, acc1[i][j], 0, 0, 0);
        }
      }
      __syncthreads();
    }

#pragma unroll
    for (int j = 0; j < 4; ++j) {
      const int col = wc1 + 16 * j + l15;
      const float bv = b1[jc + col];
#pragma unroll
      for (int i = 0; i < 2; ++i) {
#pragma unroll
        for (int r = 0; r < 4; ++r) {
          int lrow = wr1 + 16 * i + 4 * l4 + r;
          float h = 1.f / (1.f + expf(-(acc1[i][j][r] + bv)));
          unsigned short hh = f2bf(h);
          unsigned short hl = f2bf(h - bf2f(hh));
          H1h[lrow][col] = hh;
          H1l[lrow][col] = hl;
        }
      }
    }
    __syncthreads();

#pragma unroll
    for (int ks = 0; ks < 4; ++ks) {
      bf16x8 aH2 = *(const bf16x8*)&H1h[16 * wave + l15][32 * ks + 8 * l4];
      bf16x8 aL2 = *(const bf16x8*)&H1l[16 * wave + l15][32 * ks + 8 * l4];
#pragma unroll
      for (int j2 = 0; j2 < 2; ++j2) {
        const size_t wo = (size_t)(16 * j2 + l15) * HDIM + jc + 32 * ks + 8 * l4;
        bf16x8 bH2 = *(const bf16x8*)&g_w2hT[wo];
        bf16x8 bL2 = *(const bf16x8*)&g_w2lT[wo];
        acc_em[j2] = __builtin_amdgcn_mfma_f32_16x16x32_bf16(aH2, bH2, acc_em[j2], 0, 0, 0);
        acc_em[j2] = __builtin_amdgcn_mfma_f32_16x16x32_bf16(aH2, bL2, acc_em[j2], 0, 0, 0);
        acc_em[j2] = __builtin_amdgcn_mfma_f32_16x16x32_bf16(aL2, bH2, acc_em[j2], 0, 0, 0);
      }
    }
    __syncthreads();
  }

#pragma unroll
  for (int j2 = 0; j2 < 2; ++j2) {
    const int t = 16 * j2 + l15;
    const float bv = b2[t];
#pragma unroll
    for (int r = 0; r < 4; ++r) {
      int b = 16 * wave + 4 * l4 + r;
      g_em[((size_t)b * SDIM + s) * TDIM + t] = acc_em[j2][r] + bv;
    }
  }
}

// ---------------- Viterbi v5: max-tree value path, eq-scan index path,
//                  12-deep em reg-prefetch, packed bps, scalar backtrack ----
__global__ __launch_bounds__(64) void viterbi_kernel(
    const int* __restrict__ lens, const float* __restrict__ trans,
    float* __restrict__ out)
{
  __shared__ unsigned int bps32[SDIM / 4][TDIM];  // 16 KB, word w = steps 4w..4w+3
  const int b = blockIdx.x;
  const int lane = threadIdx.x;
  const int c = lane & 31;

  float tr[TDIM];
#pragma unroll
  for (int p = 0; p < TDIM; p += 4) {
    float4 t4 = *(const float4*)&trans[c * TDIM + p];
    tr[p] = t4.x; tr[p + 1] = t4.y; tr[p + 2] = t4.z; tr[p + 3] = t4.w;
  }

  int len;
  { const int* p32 = lens;
    len = (p32[1] == 0) ? (int)((const long long*)lens)[b] : p32[b]; }

  const float* emc = g_em + (size_t)b * SDIM * TDIM + c;

  float fvown = emc[0];  // t = 0
  float sfv[TDIM];
#pragma unroll
  for (int p = 0; p < TDIM; ++p) sfv[p] = readlane_f(fvown, p);

  // 12-deep register prefetch of em (t = 1..12)
  float ebuf[12];
#pragma unroll
  for (int j = 0; j < 12; ++j) ebuf[j] = emc[(size_t)(1 + j) * TDIM];

  unsigned int bpk = 0u;
  int texit = SDIM;

  // one step: PH = t&3 (compile-time), EV = prefetched em[t][c]
#define VSTEP(T, PH, EV)                                                       \
  {                                                                            \
    const int t_ = (T);                                                        \
    if (t_ >= len) { texit = t_; goto done_fwd; }                              \
    float sv[TDIM];                                                            \
    _Pragma("unroll")                                                          \
    for (int p = 0; p < TDIM; ++p) sv[p] = sfv[p] + tr[p];                     \
    float mm[16];                                                              \
    _Pragma("unroll")                                                          \
    for (int p = 0; p < 16; ++p) mm[p] = fmaxf(sv[p], sv[p + 16]);             \
    _Pragma("unroll")                                                          \
    for (int p = 0; p < 8; ++p) mm[p] = fmaxf(mm[p], mm[p + 8]);               \
    _Pragma("unroll")                                                          \
    for (int p = 0; p < 4; ++p) mm[p] = fmaxf(mm[p], mm[p + 4]);               \
    float m0 = fmaxf(fmaxf(mm[0], mm[2]), fmaxf(mm[1], mm[3]));                \
    fvown = m0 + (EV);                                                         \
    _Pragma("unroll")                                                          \
    for (int p = 0; p < TDIM; ++p) sfv[p] = readlane_f(fvown, p);              \
    int i0 = 31;                                                               \
    _Pragma("unroll")                                                          \
    for (int p = 30; p >= 0; --p) i0 = (sv[p] == m0) ? p : i0;                 \
    bpk |= (unsigned)i0 << (8 * (PH));                                         \
    if ((PH) == 3) { bps32[t_ >> 2][c] = bpk; bpk = 0u; }                      \
  }

#define LOADQ(BASE, T0)                                                        \
  {                                                                            \
    _Pragma("unroll")                                                          \
    for (int j = 0; j < 4; ++j) {                                              \
      int lt = (T0) + j; lt = lt > (SDIM - 1) ? (SDIM - 1) : lt;               \
      ebuf[(BASE) + j] = emc[(size_t)lt * TDIM];                               \
    }                                                                          \
  }

  {
    int tq = 1;
    for (; tq <= SDIM - 19; tq += 12) {  // tq = 1,13,...,493  (t = 1..504)
      VSTEP(tq + 0, 1, ebuf[0]) VSTEP(tq + 1, 2, ebuf[1])
      VSTEP(tq + 2, 3, ebuf[2]) VSTEP(tq + 3, 0, ebuf[3])
      LOADQ(0, tq + 12)
      VSTEP(tq + 4, 1, ebuf[4]) VSTEP(tq + 5, 2, ebuf[5])
      VSTEP(tq + 6, 3, ebuf[6]) VSTEP(tq + 7, 0, ebuf[7])
      LOADQ(4, tq + 16)
      VSTEP(tq + 8, 1, ebuf[8]) VSTEP(tq + 9, 2, ebuf[9])
      VSTEP(tq + 10, 3, ebuf[10]) VSTEP(tq + 11, 0, ebuf[11])
      LOADQ(8, tq + 20)
    }
    // tail: t = 505..511 use ebuf[0..6]
    VSTEP(505, 1, ebuf[0]) VSTEP(506, 2, ebuf[1]) VSTEP(507, 3, ebuf[2])
    VSTEP(508, 0, ebuf[3]) VSTEP(509, 1, ebuf[4]) VSTEP(510, 2, ebuf[5])
    VSTEP(511, 3, ebuf[6])
  }
#undef VSTEP
#undef LOADQ

done_fwd:
  {
    int w = texit >> 2, r = texit & 3;
    if (r != 0) {
#pragma unroll
      for (int j = 0; j < 4; ++j)
        if (j >= r) bpk |= (unsigned)c << (8 * j);
      bps32[w][c] = bpk;
      ++w;
    }
    const unsigned idw = (unsigned)c * 0x01010101u;
    for (; w < SDIM / 4; ++w) bps32[w][c] = idw;
  }

  // final argmax over tags (lowest index wins)
  float bs = fvown;
  int bi = c;
#pragma unroll
  for (int off = 16; off > 0; off >>= 1) {
    float os = __shfl_down(bs, off, 32);
    int oi = __shfl_down(bi, off, 32);
    if (os > bs || (os == bs && oi < bi)) { bs = os; bi = oi; }
  }
  bs = __shfl(bs, 0, 32);
  int tag = __shfl(bi, 0, 32);  // uniform

  out[(size_t)SDIM * BDIM + b] = bs;                 // all lanes, same addr+val
  out[(size_t)(SDIM - 1) * BDIM + b] = (float)tag;

  // scalar backtrack: tag uniform -> readlane walks the packed bps words
  unsigned bw_next = bps32[SDIM / 4 - 1][c];
  for (int w = SDIM / 4 - 1; w >= 0; --w) {
    unsigned bw = bw_next;
    if (w > 0) bw_next = bps32[w - 1][c];
#pragma unroll
    for (int j = 3; j >= 0; --j) {
      int t = 4 * w + j;
      if (t < 1) continue;  // only w=0, j=0
      unsigned word = (unsigned)__builtin_amdgcn_readlane((int)bw, tag);
      tag = (int)((word >> (8 * j)) & 255u);
      out[(size_t)(t - 1) * BDIM + b] = (float)tag;
    }
  }
}

// ---------------- host ----------------
static int find_by_size(const int* in_sizes, int n_in, int sz, int fb) {
  for (int i = 0; i < n_in; ++i) if (in_sizes[i] == sz) return i;
  return fb;
}

extern "C" void kernel_launch(void* const* d_in, const int* in_sizes, int n_in,
                              void* d_out, int out_size, void* d_ws, size_t ws_size,
                              hipStream_t stream) {
  const int i_hidden = find_by_size(in_sizes, n_in, SDIM * BDIM * HDIM, 0);
  const int i_lens   = find_by_size(in_sizes, n_in, BDIM, 1);
  const int i_W1     = find_by_size(in_sizes, n_in, HDIM * HDIM, 3);
  const int i_b1     = find_by_size(in_sizes, n_in, HDIM, 4);
  const int i_W2     = find_by_size(in_sizes, n_in, HDIM * TDIM, 5);
  const int i_b2     = find_by_size(in_sizes, n_in, TDIM, 6);
  const int i_tr     = find_by_size(in_sizes, n_in, TDIM * TDIM, 7);

  const float* hidden = (const float*)d_in[i_hidden];
  const int*   lens   = (const int*)d_in[i_lens];
  const float* W1     = (const float*)d_in[i_W1];
  const float* b1     = (const float*)d_in[i_b1];
  const float* W2     = (const float*)d_in[i_W2];
  const float* b2     = (const float*)d_in[i_b2];
  const float* trans  = (const float*)d_in[i_tr];
  float* out = (float*)d_out;

  split_kernel<<<HDIM + TDIM, 128, 0, stream>>>(W1, W2);
  emis_kernel<<<SDIM, 256, 0, stream>>>(hidden, b1, b2);
  viterbi_kernel<<<BDIM, 64, 0, stream>>>(lens, trans, out);
}

// Round 12
// 275.873 us; speedup vs baseline: 1.6045x; 1.0875x over previous
//
#include <hip/hip_runtime.h>
#include <math.h>

#define SDIM 512
#define BDIM 64
#define HDIM 512
#define TDIM 32
#define MTOT (SDIM * BDIM)

typedef __attribute__((ext_vector_type(8))) short bf16x8;
typedef __attribute__((ext_vector_type(4))) float f32x4;

// static device scratch
__device__ unsigned short g_w1hT[HDIM * HDIM];  // W1^T hi [n][k]
__device__ unsigned short g_w1lT[HDIM * HDIM];  // W1^T lo [n][k]
__device__ unsigned short g_w2hT[TDIM * HDIM];  // W2^T hi [t][k]
__device__ unsigned short g_w2lT[TDIM * HDIM];  // W2^T lo [t][k]
__device__ float g_em[(size_t)MTOT * TDIM];     // 4 MB emissions, b-major

__device__ __forceinline__ unsigned short f2bf(float x) {
  union { float f; unsigned int u; } v; v.f = x;
  unsigned int r = v.u + 0x7FFFu + ((v.u >> 16) & 1u);  // RNE
  return (unsigned short)(r >> 16);
}
__device__ __forceinline__ float bf2f(unsigned short h) {
  union { float f; unsigned int u; } v; v.u = ((unsigned int)h) << 16; return v.f;
}
__device__ __forceinline__ float readlane_f(float v, int l) {
  return __int_as_float(__builtin_amdgcn_readlane(__float_as_int(v), l));
}

// ---------------- W1/W2 split + transpose ----------------
__global__ void split_kernel(const float* __restrict__ W1, const float* __restrict__ W2) {
  const int n = blockIdx.x;
  const int k0 = threadIdx.x * 4;
  if (n < HDIM) {
    ushort4 h, l; float x;
    x = W1[(size_t)(k0 + 0) * HDIM + n]; h.x = f2bf(x); l.x = f2bf(x - bf2f(h.x));
    x = W1[(size_t)(k0 + 1) * HDIM + n]; h.y = f2bf(x); l.y = f2bf(x - bf2f(h.y));
    x = W1[(size_t)(k0 + 2) * HDIM + n]; h.z = f2bf(x); l.z = f2bf(x - bf2f(h.z));
    x = W1[(size_t)(k0 + 3) * HDIM + n]; h.w = f2bf(x); l.w = f2bf(x - bf2f(h.w));
    *(ushort4*)&g_w1hT[(size_t)n * HDIM + k0] = h;
    *(ushort4*)&g_w1lT[(size_t)n * HDIM + k0] = l;
  } else {
    const int t = n - HDIM;
    ushort4 h, l; float x;
    x = W2[(size_t)(k0 + 0) * TDIM + t]; h.x = f2bf(x); l.x = f2bf(x - bf2f(h.x));
    x = W2[(size_t)(k0 + 1) * TDIM + t]; h.y = f2bf(x); l.y = f2bf(x - bf2f(h.y));
    x = W2[(size_t)(k0 + 2) * TDIM + t]; h.z = f2bf(x); l.z = f2bf(x - bf2f(h.z));
    x = W2[(size_t)(k0 + 3) * TDIM + t]; h.w = f2bf(x); l.w = f2bf(x - bf2f(h.w));
    *(ushort4*)&g_w2hT[(size_t)t * HDIM + k0] = h;
    *(ushort4*)&g_w2lT[(size_t)t * HDIM + k0] = l;
  }
}

// ---------------- Fused emissions (unchanged, proven) ----------------
__global__ __launch_bounds__(256) void emis_kernel(
    const float* __restrict__ hidden, const float* __restrict__ b1,
    const float* __restrict__ b2)
{
  __shared__ unsigned short lAh[64][40];
  __shared__ unsigned short lAl[64][40];
  __shared__ unsigned short lBh[128][40];
  __shared__ unsigned short lBl[128][40];
  __shared__ unsigned short H1h[64][136];
  __shared__ unsigned short H1l[64][136];

  const int tid = threadIdx.x;
  const int s = blockIdx.x;
  const int row0 = s * 64;
  const int wave = tid >> 6;
  const int lane = tid & 63;
  const int l15 = lane & 15;
  const int l4 = lane >> 4;
  const int wr1 = (wave >> 1) * 32;
  const int wc1 = (wave & 1) * 64;

  f32x4 acc_em[2];
  acc_em[0] = (f32x4)(0.f);
  acc_em[1] = (f32x4)(0.f);

  for (int jcb = 0; jcb < 4; ++jcb) {
    const int jc = jcb * 128;

    f32x4 acc1[2][4];
#pragma unroll
    for (int i = 0; i < 2; ++i)
#pragma unroll
      for (int j = 0; j < 4; ++j) acc1[i][j] = (f32x4)(0.f);

    for (int k0 = 0; k0 < HDIM; k0 += 32) {
#pragma unroll
      for (int i = 0; i < 2; ++i) {
        int f4 = tid + 256 * i;
        int r = f4 >> 3, q = f4 & 7;
        float4 v = *(const float4*)&hidden[(size_t)(row0 + r) * HDIM + k0 + 4 * q];
        ushort4 h, l;
        h.x = f2bf(v.x); l.x = f2bf(v.x - bf2f(h.x));
        h.y = f2bf(v.y); l.y = f2bf(v.y - bf2f(h.y));
        h.z = f2bf(v.z); l.z = f2bf(v.z - bf2f(h.z));
        h.w = f2bf(v.w); l.w = f2bf(v.w - bf2f(h.w));
        *(ushort4*)&lAh[r][4 * q] = h;
        *(ushort4*)&lAl[r][4 * q] = l;
      }
#pragma unroll
      for (int i = 0; i < 2; ++i) {
        int f8 = tid + 256 * i;
        int nl = f8 >> 2, kq8 = f8 & 3;
        *(uint4*)&lBh[nl][8 * kq8] =
            *(const uint4*)&g_w1hT[(size_t)(jc + nl) * HDIM + k0 + 8 * kq8];
        *(uint4*)&lBl[nl][8 * kq8] =
            *(const uint4*)&g_w1lT[(size_t)(jc + nl) * HDIM + k0 + 8 * kq8];
      }
      __syncthreads();

      bf16x8 aH[2], aL[2];
#pragma unroll
      for (int i = 0; i < 2; ++i) {
        aH[i] = *(const bf16x8*)&lAh[wr1 + 16 * i + l15][8 * l4];
        aL[i] = *(const bf16x8*)&lAl[wr1 + 16 * i + l15][8 * l4];
      }
#pragma unroll
      for (int j = 0; j < 4; ++j) {
        bf16x8 bH = *(const bf16x8*)&lBh[wc1 + 16 * j + l15][8 * l4];
        bf16x8 bL = *(const bf16x8*)&lBl[wc1 + 16 * j + l15][8 * l4];
#pragma unroll
        for (int i = 0; i < 2; ++i) {
          acc1[i][j] = __builtin_amdgcn_mfma_f32_16x16x32_bf16(aH[i], bH, acc1[i][j], 0, 0, 0);
          acc1[i][j] = __builtin_amdgcn_mfma_f32_16x16x32_bf16(aH[i], bL, acc1[i][j], 0, 0, 0);
          acc1[i][j] = __builtin_amdgcn_mfma_f32_16x16x32_bf16(aL[i], bH, acc1[i][j], 0, 0, 0);
        }
      }
      __syncthreads();
    }

#pragma unroll
    for (int j = 0; j < 4; ++j) {
      const int col = wc1 + 16 * j + l15;
      const float bv = b1[jc + col];
#pragma unroll
      for (int i = 0; i < 2; ++i) {
#pragma unroll
        for (int r = 0; r < 4; ++r) {
          int lrow = wr1 + 16 * i + 4 * l4 + r;
          float h = 1.f / (1.f + expf(-(acc1[i][j][r] + bv)));
          unsigned short hh = f2bf(h);
          unsigned short hl = f2bf(h - bf2f(hh));
          H1h[lrow][col] = hh;
          H1l[lrow][col] = hl;
        }
      }
    }
    __syncthreads();

#pragma unroll
    for (int ks = 0; ks < 4; ++ks) {
      bf16x8 aH2 = *(const bf16x8*)&H1h[16 * wave + l15][32 * ks + 8 * l4];
      bf16x8 aL2 = *(const bf16x8*)&H1l[16 * wave + l15][32 * ks + 8 * l4];
#pragma unroll
      for (int j2 = 0; j2 < 2; ++j2) {
        const size_t wo = (size_t)(16 * j2 + l15) * HDIM + jc + 32 * ks + 8 * l4;
        bf16x8 bH2 = *(const bf16x8*)&g_w2hT[wo];
        bf16x8 bL2 = *(const bf16x8*)&g_w2lT[wo];
        acc_em[j2] = __builtin_amdgcn_mfma_f32_16x16x32_bf16(aH2, bH2, acc_em[j2], 0, 0, 0);
        acc_em[j2] = __builtin_amdgcn_mfma_f32_16x16x32_bf16(aH2, bL2, acc_em[j2], 0, 0, 0);
        acc_em[j2] = __builtin_amdgcn_mfma_f32_16x16x32_bf16(aL2, bH2, acc_em[j2], 0, 0, 0);
      }
    }
    __syncthreads();
  }

#pragma unroll
  for (int j2 = 0; j2 < 2; ++j2) {
    const int t = 16 * j2 + l15;
    const float bv = b2[t];
#pragma unroll
    for (int r = 0; r < 4; ++r) {
      int b = 16 * wave + 4 * l4 + r;
      g_em[((size_t)b * SDIM + s) * TDIM + t] = acc_em[j2][r] + bv;
    }
  }
}

// ---------------- Viterbi v6: branchless, tournament-tree argmax ----------------
__global__ __launch_bounds__(64) void viterbi_kernel(
    const int* __restrict__ lens, const float* __restrict__ trans,
    float* __restrict__ out)
{
  __shared__ unsigned int bps32[SDIM / 4][TDIM];  // 16 KB
  const int b = blockIdx.x;
  const int lane = threadIdx.x;
  const int c = lane & 31;

  float tr[TDIM];
#pragma unroll
  for (int p = 0; p < TDIM; p += 4) {
    float4 t4 = *(const float4*)&trans[c * TDIM + p];
    tr[p] = t4.x; tr[p + 1] = t4.y; tr[p + 2] = t4.z; tr[p + 3] = t4.w;
  }

  int len;
  { const int* p32 = lens;
    len = (p32[1] == 0) ? (int)((const long long*)lens)[b] : p32[b]; }

  const float* emc = g_em + (size_t)b * SDIM * TDIM + c;

  float fvown = emc[0];  // t = 0
  float sfv[TDIM];
#pragma unroll
  for (int p = 0; p < TDIM; ++p) sfv[p] = readlane_f(fvown, p);

  // 12-deep register prefetch of em (t = 1..12)
  float ebuf[12];
#pragma unroll
  for (int j = 0; j < 12; ++j) ebuf[j] = emc[(size_t)(1 + j) * TDIM];

  unsigned int bpk = 0u;

  // one step, branchless; tournament tree = first-index-wins argmax (exact)
#define VSTEP(T, PH, EV)                                                       \
  {                                                                            \
    float sv[TDIM];                                                            \
    _Pragma("unroll")                                                          \
    for (int p = 0; p < TDIM; ++p) sv[p] = sfv[p] + tr[p];                     \
    float v16[16]; int i16[16];                                                \
    _Pragma("unroll")                                                          \
    for (int p = 0; p < 16; ++p) {                                             \
      bool g = sv[2 * p] >= sv[2 * p + 1];                                     \
      v16[p] = g ? sv[2 * p] : sv[2 * p + 1];                                  \
      i16[p] = g ? 2 * p : 2 * p + 1;                                          \
    }                                                                          \
    float v8[8]; int i8[8];                                                    \
    _Pragma("unroll")                                                          \
    for (int p = 0; p < 8; ++p) {                                              \
      bool g = v16[2 * p] >= v16[2 * p + 1];                                   \
      v8[p] = g ? v16[2 * p] : v16[2 * p + 1];                                 \
      i8[p] = g ? i16[2 * p] : i16[2 * p + 1];                                 \
    }                                                                          \
    float v4[4]; int i4[4];                                                    \
    _Pragma("unroll")                                                          \
    for (int p = 0; p < 4; ++p) {                                              \
      bool g = v8[2 * p] >= v8[2 * p + 1];                                     \
      v4[p] = g ? v8[2 * p] : v8[2 * p + 1];                                   \
      i4[p] = g ? i8[2 * p] : i8[2 * p + 1];                                   \
    }                                                                          \
    bool ga = v4[0] >= v4[1];                                                  \
    float va = ga ? v4[0] : v4[1]; int ia = ga ? i4[0] : i4[1];                \
    bool gb = v4[2] >= v4[3];                                                  \
    float vb = gb ? v4[2] : v4[3]; int ib = gb ? i4[2] : i4[3];                \
    bool gf = va >= vb;                                                        \
    float m0 = gf ? va : vb; int i0 = gf ? ia : ib;                            \
    const bool act = (T) < len;                                                \
    fvown = act ? (m0 + (EV)) : fvown;                                         \
    int bp = act ? i0 : c;                                                     \
    _Pragma("unroll")                                                          \
    for (int p = 0; p < TDIM; ++p) sfv[p] = readlane_f(fvown, p);              \
    bpk |= (unsigned)bp << (8 * (PH));                                         \
    if ((PH) == 3) { bps32[(T) >> 2][c] = bpk; bpk = 0u; }                     \
  }

#define LOADQ(BASE, T0)                                                        \
  {                                                                            \
    _Pragma("unroll")                                                          \
    for (int j = 0; j < 4; ++j) {                                              \
      int lt = (T0) + j; lt = lt > (SDIM - 1) ? (SDIM - 1) : lt;               \
      ebuf[(BASE) + j] = emc[(size_t)lt * TDIM];                               \
    }                                                                          \
  }

  {
    int tq = 1;
    for (; tq <= SDIM - 19; tq += 12) {  // t = 1..504
      VSTEP(tq + 0, 1, ebuf[0]) VSTEP(tq + 1, 2, ebuf[1])
      VSTEP(tq + 2, 3, ebuf[2]) VSTEP(tq + 3, 0, ebuf[3])
      LOADQ(0, tq + 12)
      VSTEP(tq + 4, 1, ebuf[4]) VSTEP(tq + 5, 2, ebuf[5])
      VSTEP(tq + 6, 3, ebuf[6]) VSTEP(tq + 7, 0, ebuf[7])
      LOADQ(4, tq + 16)
      VSTEP(tq + 8, 1, ebuf[8]) VSTEP(tq + 9, 2, ebuf[9])
      VSTEP(tq + 10, 3, ebuf[10]) VSTEP(tq + 11, 0, ebuf[11])
      LOADQ(8, tq + 20)
    }
    // tail: t = 505..511
    VSTEP(505, 1, ebuf[0]) VSTEP(506, 2, ebuf[1]) VSTEP(507, 3, ebuf[2])
    VSTEP(508, 0, ebuf[3]) VSTEP(509, 1, ebuf[4]) VSTEP(510, 2, ebuf[5])
    VSTEP(511, 3, ebuf[6])
  }
#undef VSTEP
#undef LOADQ

  // final argmax over tags (lowest index wins)
  float bs = fvown;
  int bi = c;
#pragma unroll
  for (int off = 16; off > 0; off >>= 1) {
    float os = __shfl_down(bs, off, 32);
    int oi = __shfl_down(bi, off, 32);
    if (os > bs || (os == bs && oi < bi)) { bs = os; bi = oi; }
  }
  bs = __shfl(bs, 0, 32);
  int tag = __shfl(bi, 0, 32);  // uniform

  out[(size_t)SDIM * BDIM + b] = bs;
  out[(size_t)(SDIM - 1) * BDIM + b] = (float)tag;

  // scalar backtrack via readlane over packed bps words
  unsigned bw_next = bps32[SDIM / 4 - 1][c];
  for (int w = SDIM / 4 - 1; w >= 0; --w) {
    unsigned bw = bw_next;
    if (w > 0) bw_next = bps32[w - 1][c];
#pragma unroll
    for (int j = 3; j >= 0; --j) {
      int t = 4 * w + j;
      if (t < 1) continue;
      unsigned word = (unsigned)__builtin_amdgcn_readlane((int)bw, tag);
      tag = (int)((word >> (8 * j)) & 255u);
      out[(size_t)(t - 1) * BDIM + b] = (float)tag;
    }
  }
}

// ---------------- host ----------------
static int find_by_size(const int* in_sizes, int n_in, int sz, int fb) {
  for (int i = 0; i < n_in; ++i) if (in_sizes[i] == sz) return i;
  return fb;
}

extern "C" void kernel_launch(void* const* d_in, const int* in_sizes, int n_in,
                              void* d_out, int out_size, void* d_ws, size_t ws_size,
                              hipStream_t stream) {
  const int i_hidden = find_by_size(in_sizes, n_in, SDIM * BDIM * HDIM, 0);
  const int i_lens   = find_by_size(in_sizes, n_in, BDIM, 1);
  const int i_W1     = find_by_size(in_sizes, n_in, HDIM * HDIM, 3);
  const int i_b1     = find_by_size(in_sizes, n_in, HDIM, 4);
  const int i_W2     = find_by_size(in_sizes, n_in, HDIM * TDIM, 5);
  const int i_b2     = find_by_size(in_sizes, n_in, TDIM, 6);
  const int i_tr     = find_by_size(in_sizes, n_in, TDIM * TDIM, 7);

  const float* hidden = (const float*)d_in[i_hidden];
  const int*   lens   = (const int*)d_in[i_lens];
  const float* W1     = (const float*)d_in[i_W1];
  const float* b1     = (const float*)d_in[i_b1];
  const float* W2     = (const float*)d_in[i_W2];
  const float* b2     = (const float*)d_in[i_b2];
  const float* trans  = (const float*)d_in[i_tr];
  float* out = (float*)d_out;

  split_kernel<<<HDIM + TDIM, 128, 0, stream>>>(W1, W2);
  emis_kernel<<<SDIM, 256, 0, stream>>>(hidden, b1, b2);
  viterbi_kernel<<<BDIM, 64, 0, stream>>>(lens, trans, out);
}

// Round 13
// 239.406 us; speedup vs baseline: 1.8489x; 1.1523x over previous
//
#include <hip/hip_runtime.h>
#include <math.h>

#define SDIM 512
#define BDIM 64
#define HDIM 512
#define TDIM 32
#define MTOT (SDIM * BDIM)

typedef __attribute__((ext_vector_type(8))) short bf16x8;
typedef __attribute__((ext_vector_type(4))) float f32x4;

// static device scratch
__device__ unsigned short g_w1hT[HDIM * HDIM];  // W1^T hi [n][k]
__device__ unsigned short g_w1lT[HDIM * HDIM];  // W1^T lo [n][k]
__device__ unsigned short g_w2hT[TDIM * HDIM];  // W2^T hi [t][k]
__device__ unsigned short g_w2lT[TDIM * HDIM];  // W2^T lo [t][k]
__device__ float g_em[(size_t)MTOT * TDIM];     // 4 MB emissions, b-major

__device__ __forceinline__ unsigned short f2bf(float x) {
  union { float f; unsigned int u; } v; v.f = x;
  unsigned int r = v.u + 0x7FFFu + ((v.u >> 16) & 1u);  // RNE
  return (unsigned short)(r >> 16);
}
__device__ __forceinline__ float bf2f(unsigned short h) {
  union { float f; unsigned int u; } v; v.u = ((unsigned int)h) << 16; return v.f;
}
__device__ __forceinline__ float fmax3(float a, float b, float c) {
  return fmaxf(fmaxf(a, b), c);  // fuses to v_max3_f32
}
__device__ __forceinline__ int imin3(int a, int b, int c) {
  int m = a < b ? a : b; return m < c ? m : c;  // fuses to v_min3_i32
}

// ---------------- W1/W2 split + transpose ----------------
__global__ void split_kernel(const float* __restrict__ W1, const float* __restrict__ W2) {
  const int n = blockIdx.x;
  const int k0 = threadIdx.x * 4;
  if (n < HDIM) {
    ushort4 h, l; float x;
    x = W1[(size_t)(k0 + 0) * HDIM + n]; h.x = f2bf(x); l.x = f2bf(x - bf2f(h.x));
    x = W1[(size_t)(k0 + 1) * HDIM + n]; h.y = f2bf(x); l.y = f2bf(x - bf2f(h.y));
    x = W1[(size_t)(k0 + 2) * HDIM + n]; h.z = f2bf(x); l.z = f2bf(x - bf2f(h.z));
    x = W1[(size_t)(k0 + 3) * HDIM + n]; h.w = f2bf(x); l.w = f2bf(x - bf2f(h.w));
    *(ushort4*)&g_w1hT[(size_t)n * HDIM + k0] = h;
    *(ushort4*)&g_w1lT[(size_t)n * HDIM + k0] = l;
  } else {
    const int t = n - HDIM;
    ushort4 h, l; float x;
    x = W2[(size_t)(k0 + 0) * TDIM + t]; h.x = f2bf(x); l.x = f2bf(x - bf2f(h.x));
    x = W2[(size_t)(k0 + 1) * TDIM + t]; h.y = f2bf(x); l.y = f2bf(x - bf2f(h.y));
    x = W2[(size_t)(k0 + 2) * TDIM + t]; h.z = f2bf(x); l.z = f2bf(x - bf2f(h.z));
    x = W2[(size_t)(k0 + 3) * TDIM + t]; h.w = f2bf(x); l.w = f2bf(x - bf2f(h.w));
    *(ushort4*)&g_w2hT[(size_t)t * HDIM + k0] = h;
    *(ushort4*)&g_w2lT[(size_t)t * HDIM + k0] = l;
  }
}

// ---------------- Fused emissions (unchanged, proven) ----------------
__global__ __launch_bounds__(256) void emis_kernel(
    const float* __restrict__ hidden, const float* __restrict__ b1,
    const float* __restrict__ b2)
{
  __shared__ unsigned short lAh[64][40];
  __shared__ unsigned short lAl[64][40];
  __shared__ unsigned short lBh[128][40];
  __shared__ unsigned short lBl[128][40];
  __shared__ unsigned short H1h[64][136];
  __shared__ unsigned short H1l[64][136];

  const int tid = threadIdx.x;
  const int s = blockIdx.x;
  const int row0 = s * 64;
  const int wave = tid >> 6;
  const int lane = tid & 63;
  const int l15 = lane & 15;
  const int l4 = lane >> 4;
  const int wr1 = (wave >> 1) * 32;
  const int wc1 = (wave & 1) * 64;

  f32x4 acc_em[2];
  acc_em[0] = (f32x4)(0.f);
  acc_em[1] = (f32x4)(0.f);

  for (int jcb = 0; jcb < 4; ++jcb) {
    const int jc = jcb * 128;

    f32x4 acc1[2][4];
#pragma unroll
    for (int i = 0; i < 2; ++i)
#pragma unroll
      for (int j = 0; j < 4; ++j) acc1[i][j] = (f32x4)(0.f);

    for (int k0 = 0; k0 < HDIM; k0 += 32) {
#pragma unroll
      for (int i = 0; i < 2; ++i) {
        int f4 = tid + 256 * i;
        int r = f4 >> 3, q = f4 & 7;
        float4 v = *(const float4*)&hidden[(size_t)(row0 + r) * HDIM + k0 + 4 * q];
        ushort4 h, l;
        h.x = f2bf(v.x); l.x = f2bf(v.x - bf2f(h.x));
        h.y = f2bf(v.y); l.y = f2bf(v.y - bf2f(h.y));
        h.z = f2bf(v.z); l.z = f2bf(v.z - bf2f(h.z));
        h.w = f2bf(v.w); l.w = f2bf(v.w - bf2f(h.w));
        *(ushort4*)&lAh[r][4 * q] = h;
        *(ushort4*)&lAl[r][4 * q] = l;
      }
#pragma unroll
      for (int i = 0; i < 2; ++i) {
        int f8 = tid + 256 * i;
        int nl = f8 >> 2, kq8 = f8 & 3;
        *(uint4*)&lBh[nl][8 * kq8] =
            *(const uint4*)&g_w1hT[(size_t)(jc + nl) * HDIM + k0 + 8 * kq8];
        *(uint4*)&lBl[nl][8 * kq8] =
            *(const uint4*)&g_w1lT[(size_t)(jc + nl) * HDIM + k0 + 8 * kq8];
      }
      __syncthreads();

      bf16x8 aH[2], aL[2];
#pragma unroll
      for (int i = 0; i < 2; ++i) {
        aH[i] = *(const bf16x8*)&lAh[wr1 + 16 * i + l15][8 * l4];
        aL[i] = *(const bf16x8*)&lAl[wr1 + 16 * i + l15][8 * l4];
      }
#pragma unroll
      for (int j = 0; j < 4; ++j) {
        bf16x8 bH = *(const bf16x8*)&lBh[wc1 + 16 * j + l15][8 * l4];
        bf16x8 bL = *(const bf16x8*)&lBl[wc1 + 16 * j + l15][8 * l4];
#pragma unroll
        for (int i = 0; i < 2; ++i) {
          acc1[i][j] = __builtin_amdgcn_mfma_f32_16x16x32_bf16(aH[i], bH, acc1[i][j], 0, 0, 0);
          acc1[i][j] = __builtin_amdgcn_mfma_f32_16x16x32_bf16(aH[i], bL, acc1[i][j], 0, 0, 0);
          acc1[i][j] = __builtin_amdgcn_mfma_f32_16x16x32_bf16(aL[i], bH, acc1[i][j], 0, 0, 0);
        }
      }
      __syncthreads();
    }

#pragma unroll
    for (int j = 0; j < 4; ++j) {
      const int col = wc1 + 16 * j + l15;
      const float bv = b1[jc + col];
#pragma unroll
      for (int i = 0; i < 2; ++i) {
#pragma unroll
        for (int r = 0; r < 4; ++r) {
          int lrow = wr1 + 16 * i + 4 * l4 + r;
          float h = 1.f / (1.f + expf(-(acc1[i][j][r] + bv)));
          unsigned short hh = f2bf(h);
          unsigned short hl = f2bf(h - bf2f(hh));
          H1h[lrow][col] = hh;
          H1l[lrow][col] = hl;
        }
      }
    }
    __syncthreads();

#pragma unroll
    for (int ks = 0; ks < 4; ++ks) {
      bf16x8 aH2 = *(const bf16x8*)&H1h[16 * wave + l15][32 * ks + 8 * l4];
      bf16x8 aL2 = *(const bf16x8*)&H1l[16 * wave + l15][32 * ks + 8 * l4];
#pragma unroll
      for (int j2 = 0; j2 < 2; ++j2) {
        const size_t wo = (size_t)(16 * j2 + l15) * HDIM + jc + 32 * ks + 8 * l4;
        bf16x8 bH2 = *(const bf16x8*)&g_w2hT[wo];
        bf16x8 bL2 = *(const bf16x8*)&g_w2lT[wo];
        acc_em[j2] = __builtin_amdgcn_mfma_f32_16x16x32_bf16(aH2, bH2, acc_em[j2], 0, 0, 0);
        acc_em[j2] = __builtin_amdgcn_mfma_f32_16x16x32_bf16(aH2, bL2, acc_em[j2], 0, 0, 0);
        acc_em[j2] = __builtin_amdgcn_mfma_f32_16x16x32_bf16(aL2, bH2, acc_em[j2], 0, 0, 0);
      }
    }
    __syncthreads();
  }

#pragma unroll
  for (int j2 = 0; j2 < 2; ++j2) {
    const int t = 16 * j2 + l15;
    const float bv = b2[t];
#pragma unroll
    for (int r = 0; r < 4; ++r) {
      int b = 16 * wave + 4 * l4 + r;
      g_em[((size_t)b * SDIM + s) * TDIM + t] = acc_em[j2][r] + bv;
    }
  }
}

// ---------------- Viterbi v7: h-split halves, LDS fv broadcast, max3/min3 trees ----------------
__global__ __launch_bounds__(64) void viterbi_kernel(
    const int* __restrict__ lens, const float* __restrict__ trans,
    float* __restrict__ out)
{
  __shared__ float fvL[64];                       // [0..31] canonical, [32..63] dup
  __shared__ unsigned int bps32[SDIM / 4][TDIM];  // 16 KB
  const int b = blockIdx.x;
  const int lane = threadIdx.x;
  const int c = lane & 31;
  const int h = lane >> 5;
  const int p0 = 16 * h;  // this half's prev range [p0, p0+16)

  // tr[j] = trans[c][p0 + j]
  float tr[16];
#pragma unroll
  for (int j = 0; j < 16; j += 4) {
    float4 t4 = *(const float4*)&trans[c * TDIM + p0 + j];
    tr[j] = t4.x; tr[j + 1] = t4.y; tr[j + 2] = t4.z; tr[j + 3] = t4.w;
  }

  int len;
  { const int* p32 = lens;
    len = (p32[1] == 0) ? (int)((const long long*)lens)[b] : p32[b]; }

  const float* emc = g_em + (size_t)b * SDIM * TDIM + c;

  float fvown = emc[0];  // t = 0 (lanes c and c+32 load the same)
  fvL[lane] = fvown;

  // 12-deep register prefetch of em (t = 1..12)
  float ebuf[12];
#pragma unroll
  for (int j = 0; j < 12; ++j) ebuf[j] = emc[(size_t)(1 + j) * TDIM];

  unsigned int bpk = 0u;

  // one step: h-split candidates, value via max3 tree, index via eq+min3
#define VSTEP(T, PH, EV)                                                       \
  {                                                                            \
    float4 q0 = *(const float4*)&fvL[p0];                                      \
    float4 q1 = *(const float4*)&fvL[p0 + 4];                                  \
    float4 q2 = *(const float4*)&fvL[p0 + 8];                                  \
    float4 q3 = *(const float4*)&fvL[p0 + 12];                                 \
    float sv[16];                                                              \
    sv[0] = q0.x + tr[0];  sv[1] = q0.y + tr[1];                               \
    sv[2] = q0.z + tr[2];  sv[3] = q0.w + tr[3];                               \
    sv[4] = q1.x + tr[4];  sv[5] = q1.y + tr[5];                               \
    sv[6] = q1.z + tr[6];  sv[7] = q1.w + tr[7];                               \
    sv[8] = q2.x + tr[8];  sv[9] = q2.y + tr[9];                               \
    sv[10] = q2.z + tr[10]; sv[11] = q2.w + tr[11];                            \
    sv[12] = q3.x + tr[12]; sv[13] = q3.y + tr[13];                            \
    sv[14] = q3.z + tr[14]; sv[15] = q3.w + tr[15];                            \
    float l0 = fmax3(sv[0], sv[1], sv[2]);                                     \
    float l1 = fmax3(sv[3], sv[4], sv[5]);                                     \
    float l2 = fmax3(sv[6], sv[7], sv[8]);                                     \
    float l3 = fmax3(sv[9], sv[10], sv[11]);                                   \
    float l4 = fmax3(sv[12], sv[13], sv[14]);                                  \
    float mh = fmaxf(fmax3(l0, l1, l2), fmax3(l3, l4, sv[15]));                \
    float mo = __shfl_xor(mh, 32, 64);                                         \
    float m0 = fmaxf(mh, mo);                                                  \
    const bool act = (T) < len;                                                \
    fvown = act ? (m0 + (EV)) : fvown;                                         \
    fvL[lane] = fvown;  /* early write; index path below covers latency */     \
    int i_[16];                                                                \
    _Pragma("unroll")                                                          \
    for (int j = 0; j < 16; ++j) i_[j] = (sv[j] == m0) ? j : 63;               \
    int u0 = imin3(i_[0], i_[1], i_[2]);                                       \
    int u1 = imin3(i_[3], i_[4], i_[5]);                                       \
    int u2 = imin3(i_[6], i_[7], i_[8]);                                       \
    int u3 = imin3(i_[9], i_[10], i_[11]);                                     \
    int u4 = imin3(i_[12], i_[13], i_[14]);                                    \
    int jm = imin3(imin3(u0, u1, u2), imin3(u3, u4, i_[15]), 63);              \
    int gi = (jm == 63) ? 255 : (p0 + jm);                                     \
    int go = __shfl_xor(gi, 32, 64);                                           \
    int im = gi < go ? gi : go;                                                \
    int bp = act ? im : c;                                                     \
    bpk |= (unsigned)bp << (8 * (PH));                                         \
    if ((PH) == 3) { bps32[(T) >> 2][c] = bpk; bpk = 0u; }                     \
  }

#define LOADQ(BASE, T0)                                                        \
  {                                                                            \
    _Pragma("unroll")                                                          \
    for (int j = 0; j < 4; ++j) {                                              \
      int lt = (T0) + j; lt = lt > (SDIM - 1) ? (SDIM - 1) : lt;               \
      ebuf[(BASE) + j] = emc[(size_t)lt * TDIM];                               \
    }                                                                          \
  }

  {
    int tq = 1;
    for (; tq <= SDIM - 19; tq += 12) {  // t = 1..504
      VSTEP(tq + 0, 1, ebuf[0]) VSTEP(tq + 1, 2, ebuf[1])
      VSTEP(tq + 2, 3, ebuf[2]) VSTEP(tq + 3, 0, ebuf[3])
      LOADQ(0, tq + 12)
      VSTEP(tq + 4, 1, ebuf[4]) VSTEP(tq + 5, 2, ebuf[5])
      VSTEP(tq + 6, 3, ebuf[6]) VSTEP(tq + 7, 0, ebuf[7])
      LOADQ(4, tq + 16)
      VSTEP(tq + 8, 1, ebuf[8]) VSTEP(tq + 9, 2, ebuf[9])
      VSTEP(tq + 10, 3, ebuf[10]) VSTEP(tq + 11, 0, ebuf[11])
      LOADQ(8, tq + 20)
    }
    // tail: t = 505..511
    VSTEP(505, 1, ebuf[0]) VSTEP(506, 2, ebuf[1]) VSTEP(507, 3, ebuf[2])
    VSTEP(508, 0, ebuf[3]) VSTEP(509, 1, ebuf[4]) VSTEP(510, 2, ebuf[5])
    VSTEP(511, 3, ebuf[6])
  }
#undef VSTEP
#undef LOADQ

  // final argmax over tags (lowest index wins); fvown identical across halves
  float bs = fvown;
  int bi = c;
#pragma unroll
  for (int off = 16; off > 0; off >>= 1) {
    float os = __shfl_down(bs, off, 32);
    int oi = __shfl_down(bi, off, 32);
    if (os > bs || (os == bs && oi < bi)) { bs = os; bi = oi; }
  }
  bs = __shfl(bs, 0, 32);
  int tag = __shfl(bi, 0, 32);  // uniform

  out[(size_t)SDIM * BDIM + b] = bs;
  out[(size_t)(SDIM - 1) * BDIM + b] = (float)tag;

  // scalar backtrack via readlane over packed bps words
  unsigned bw_next = bps32[SDIM / 4 - 1][c];
  for (int w = SDIM / 4 - 1; w >= 0; --w) {
    unsigned bw = bw_next;
    if (w > 0) bw_next = bps32[w - 1][c];
#pragma unroll
    for (int j = 3; j >= 0; --j) {
      int t = 4 * w + j;
      if (t < 1) continue;
      unsigned word = (unsigned)__builtin_amdgcn_readlane((int)bw, tag);
      tag = (int)((word >> (8 * j)) & 255u);
      out[(size_t)(t - 1) * BDIM + b] = (float)tag;
    }
  }
}

// ---------------- host ----------------
static int find_by_size(const int* in_sizes, int n_in, int sz, int fb) {
  for (int i = 0; i < n_in; ++i) if (in_sizes[i] == sz) return i;
  return fb;
}

extern "C" void kernel_launch(void* const* d_in, const int* in_sizes, int n_in,
                              void* d_out, int out_size, void* d_ws, size_t ws_size,
                              hipStream_t stream) {
  const int i_hidden = find_by_size(in_sizes, n_in, SDIM * BDIM * HDIM, 0);
  const int i_lens   = find_by_size(in_sizes, n_in, BDIM, 1);
  const int i_W1     = find_by_size(in_sizes, n_in, HDIM * HDIM, 3);
  const int i_b1     = find_by_size(in_sizes, n_in, HDIM, 4);
  const int i_W2     = find_by_size(in_sizes, n_in, HDIM * TDIM, 5);
  const int i_b2     = find_by_size(in_sizes, n_in, TDIM, 6);
  const int i_tr     = find_by_size(in_sizes, n_in, TDIM * TDIM, 7);

  const float* hidden = (const float*)d_in[i_hidden];
  const int*   lens   = (const int*)d_in[i_lens];
  const float* W1     = (const float*)d_in[i_W1];
  const float* b1     = (const float*)d_in[i_b1];
  const float* W2     = (const float*)d_in[i_W2];
  const float* b2     = (const float*)d_in[i_b2];
  const float* trans  = (const float*)d_in[i_tr];
  float* out = (float*)d_out;

  split_kernel<<<HDIM + TDIM, 128, 0, stream>>>(W1, W2);
  emis_kernel<<<SDIM, 256, 0, stream>>>(hidden, b1, b2);
  viterbi_kernel<<<BDIM, 64, 0, stream>>>(lens, trans, out);
}